// Round 4
// baseline (7714.259 us; speedup 1.0000x reference)
//
#include <hip/hip_runtime.h>
#include <math.h>

// Problem constants
#define FF   81919
#define CC   16384
#define HH   512
#define NLL  2
#define GG   5
#define LAMF 0.01f

#define CH   (CC * HH)   // elements per state matrix

// d_out layout (float32, real parts only — harness casts complex64 -> float32):
//   [0, FF)               out.real
//   [FF, FF+CH)           h0.real
//   [FF+CH, FF+2CH)       h1.real
//
// d_ws per-chunk layout (float2 complex): stk[M*25] | Xc[M*512] | Gc[M*1536]
//   = M * 2073 complex = 16.6 KB/row. M chosen at runtime from ws_size.

// ---------------------------------------------------------------------------
__device__ __forceinline__ float2 cmulf2(float2 a, float2 b) {
    return make_float2(a.x * b.x - a.y * b.y, a.x * b.y + a.y * b.x);
}
__device__ __forceinline__ float2 caddf2(float2 a, float2 b) {
    return make_float2(a.x + b.x, a.y + b.y);
}
__device__ __forceinline__ float sigmoidf_(float x) {
    return 1.0f / (1.0f + expf(-x));
}

// ---------------------------------------------------------------------------
// 1) prep (per chunk): stk[c*25 + g*5 + n] = log-compressed stack for global
//    row r0+c; pos = (r0+c)*5 + g; chan n: 0 -> x, 1..4 -> extras[n-1];
//    pos == FF (single right-pad) -> 0
// ---------------------------------------------------------------------------
__global__ __launch_bounds__(256) void prep_kernel(const float2* __restrict__ x,
                                                   const float2* __restrict__ extras,
                                                   float2* __restrict__ stk,
                                                   int r0, int m) {
    int i = blockIdx.x * 256 + threadIdx.x;           // [0, m*25)
    if (i >= m * 25) return;
    int c = i / 25, j = i - c * 25;
    int g = j / 5, n = j - g * 5;
    int pos = (r0 + c) * 5 + g;
    float2 v = make_float2(0.f, 0.f);
    if (pos < FF) {
        v = (n == 0) ? x[pos] : extras[(size_t)(n - 1) * FF + pos];
    }
    float r = sqrtf(v.x * v.x + v.y * v.y);
    float sc = (r > 0.f) ? (log1pf(r) / r) : 0.f;
    stk[i] = make_float2(v.x * sc, v.y * sc);
}

// ---------------------------------------------------------------------------
// 2) complex fp32 GEMM: C[M,N] = (ACC ? C : 0) + A[M,K] @ B[K,N] (+bias)
//    row-major float2, BM=BN=64, BK=16, 256 threads, 4x4 complex per thread
//    M,N multiples of 64; K arbitrary (guarded)
// ---------------------------------------------------------------------------
#define BM 64
#define BN 64
#define BK 16

template <bool ACC, bool BIAS>
__global__ __launch_bounds__(256) void cgemm_kernel(const float2* __restrict__ A, int lda,
                                                    const float2* __restrict__ B, int ldb,
                                                    const float2* __restrict__ bias,
                                                    float2* __restrict__ C, int ldc,
                                                    int K) {
    __shared__ float2 As[BK][BM + 1];
    __shared__ float2 Bs[BK][BN + 1];

    int bx = blockIdx.x, by = blockIdx.y;
    int t = threadIdx.x;
    int tx = t & 15, ty = t >> 4;
    int row0 = by * BM + ty * 4;
    int col0 = bx * BN + tx * 4;

    float2 acc[4][4];
#pragma unroll
    for (int i = 0; i < 4; i++)
#pragma unroll
        for (int j = 0; j < 4; j++) acc[i][j] = make_float2(0.f, 0.f);

    int am = t >> 2, ak4 = (t & 3) * 4;   // A tile: 64 rows x 16 k
    int bk = t >> 4, bn4 = (t & 15) * 4;  // B tile: 16 k x 64 cols

    const float2* Arow = A + (size_t)(by * BM + am) * lda;
    const float2* Bcol = B + (size_t)(bx * BN) + bn4;

    for (int k0 = 0; k0 < K; k0 += BK) {
#pragma unroll
        for (int i = 0; i < 4; i++) {
            int k = k0 + ak4 + i;
            As[ak4 + i][am] = (k < K) ? Arow[k] : make_float2(0.f, 0.f);
        }
        {
            int k = k0 + bk;
            const float2* bp = Bcol + (size_t)k * ldb;
#pragma unroll
            for (int j = 0; j < 4; j++) {
                Bs[bk][bn4 + j] = (k < K) ? bp[j] : make_float2(0.f, 0.f);
            }
        }
        __syncthreads();
#pragma unroll
        for (int kk = 0; kk < BK; kk++) {
            float2 a[4], b[4];
#pragma unroll
            for (int i = 0; i < 4; i++) a[i] = As[kk][ty * 4 + i];
#pragma unroll
            for (int j = 0; j < 4; j++) b[j] = Bs[kk][tx * 4 + j];
#pragma unroll
            for (int i = 0; i < 4; i++)
#pragma unroll
                for (int j = 0; j < 4; j++) {
                    acc[i][j].x = fmaf(a[i].x, b[j].x, fmaf(-a[i].y, b[j].y, acc[i][j].x));
                    acc[i][j].y = fmaf(a[i].x, b[j].y, fmaf(a[i].y, b[j].x, acc[i][j].y));
                }
        }
        __syncthreads();
    }

#pragma unroll
    for (int i = 0; i < 4; i++) {
        float2* crow = C + (size_t)(row0 + i) * ldc + col0;
#pragma unroll
        for (int j = 0; j < 4; j++) {
            float2 v = acc[i][j];
            if (BIAS) {
                float2 bb = bias[col0 + j];
                v.x += bb.x; v.y += bb.y;
            }
            if (ACC) {
                float2 cc = crow[j];
                v.x += cc.x; v.y += cc.y;
            }
            crow[j] = v;
        }
    }
}

// ---------------------------------------------------------------------------
// 3) ew1 (per chunk): Gc[c][H+k] <- sigmoid(Gc[c][H+k]) * state[c][k]
//    Gc row-major [m][1536]; state rows = h layer rows r0..r0+m
// ---------------------------------------------------------------------------
__global__ __launch_bounds__(256) void ew1_kernel(float2* __restrict__ Gc,
                                                  const float2* __restrict__ state) {
    int i = blockIdx.x * 256 + threadIdx.x;  // [0, m*HH)
    int c = i >> 9, k = i & (HH - 1);
    size_t gi = (size_t)c * (3 * HH) + HH + k;
    float2 raw = Gc[gi];
    float2 r = make_float2(sigmoidf_(raw.x), sigmoidf_(raw.y));
    float2 s = state[i];
    Gc[gi] = cmulf2(r, s);
}

// ---------------------------------------------------------------------------
// 4) ew2 (per chunk): z = sig(Gc[:,:H]); a = tanh(Gc[:,2H:]);
//    hnew = (1-z)*state + z*a ; Xc <- hnew (complex, feeds next stage);
//    outr <- hnew.re (float, into d_out)
// ---------------------------------------------------------------------------
__global__ __launch_bounds__(256) void ew2_kernel(const float2* __restrict__ Gc,
                                                  const float2* __restrict__ state,
                                                  float2* __restrict__ Xc,
                                                  float* __restrict__ outr) {
    int i = blockIdx.x * 256 + threadIdx.x;  // [0, m*HH)
    int c = i >> 9, k = i & (HH - 1);
    float2 zraw = Gc[(size_t)c * (3 * HH) + k];
    float2 araw = Gc[(size_t)c * (3 * HH) + 2 * HH + k];
    float2 z = make_float2(sigmoidf_(zraw.x), sigmoidf_(zraw.y));
    float2 a = make_float2(tanhf(araw.x), tanhf(araw.y));
    float2 s = state[i];
    float2 omz = make_float2(1.f - z.x, -z.y);
    float2 hn = caddf2(cmulf2(omz, s), cmulf2(z, a));
    Xc[i]   = hn;
    outr[i] = hn.x;
}

// ---------------------------------------------------------------------------
// 5) output matmul (per chunk): y = Xc[c,:] . w_out[:,g] + b_out[g];
//    p = (r0+c)*5+g; if p < FF: out[p] = -LAM * Re(y); one wave per (c,g)
// ---------------------------------------------------------------------------
__global__ __launch_bounds__(256) void outmm_kernel(const float2* __restrict__ Xc,
                                                    const float2* __restrict__ w_out,
                                                    const float2* __restrict__ b_out,
                                                    float* __restrict__ out,
                                                    int r0, int m) {
    int wid = (blockIdx.x * 256 + threadIdx.x) >> 6;  // chunk-local wave id
    int lane = threadIdx.x & 63;
    if (wid >= m * GG) return;
    int c = wid / GG, g = wid - c * GG;
    const float2* arow = Xc + (size_t)c * HH;
    float2 acc = make_float2(0.f, 0.f);
    for (int k = lane; k < HH; k += 64) {
        acc = caddf2(acc, cmulf2(arow[k], w_out[k * GG + g]));
    }
#pragma unroll
    for (int off = 32; off > 0; off >>= 1) {
        acc.x += __shfl_down(acc.x, off);
        acc.y += __shfl_down(acc.y, off);
    }
    if (lane == 0) {
        int p = (r0 + c) * GG + g;
        if (p < FF) {
            out[p] = -LAMF * (acc.x + b_out[g].x);
        }
    }
}

// ---------------------------------------------------------------------------
// launch
// ---------------------------------------------------------------------------
extern "C" void kernel_launch(void* const* d_in, const int* in_sizes, int n_in,
                              void* d_out, int out_size, void* d_ws, size_t ws_size,
                              hipStream_t stream) {
    const float2* x      = (const float2*)d_in[0];
    const float2* extras = (const float2*)d_in[1];
    const float2* h      = (const float2*)d_in[2];
    const float2* w_in   = (const float2*)d_in[3];
    const float2* b_in   = (const float2*)d_in[4];
    const float2* w_i    = (const float2*)d_in[5];
    const float2* w_h    = (const float2*)d_in[6];
    const float2* b_rnn  = (const float2*)d_in[7];
    const float2* w_out  = (const float2*)d_in[8];
    const float2* b_out  = (const float2*)d_in[9];

    float* outf   = (float*)d_out;        // [FF] out.real
    float* houtr0 = outf + FF;            // [CH] h0.real
    float* houtr1 = houtr0 + (size_t)CH;  // [CH] h1.real

    // runtime chunk selection: M*(25+512+1536) complex must fit in ws
    int chunk = 2048;
    while (chunk > 64 && (size_t)chunk * 2073 * sizeof(float2) > ws_size) chunk >>= 1;
    int nch = CC / chunk;

    float2* stk = (float2*)d_ws;                 // [chunk*25]
    float2* Xc  = stk + (size_t)chunk * 25;      // [chunk*512]
    float2* Gc  = Xc + (size_t)chunk * HH;       // [chunk*1536]

    for (int cb = 0; cb < nch; cb++) {
        int r0 = cb * chunk;
        size_t off = (size_t)r0 * HH;

        // prep -> stk
        prep_kernel<<<(chunk * 25 + 255) / 256, 256, 0, stream>>>(x, extras, stk, r0, chunk);
        // Xc = stk @ w_in + b_in   (K=25)
        cgemm_kernel<false, true><<<dim3(HH / BN, chunk / BM), 256, 0, stream>>>(
            stk, 25, w_in, HH, b_in, Xc, HH, 25);

        for (int l = 0; l < NLL; l++) {
            const float2* sl  = h + (size_t)l * CH + off;            // state rows
            const float2* wil = w_i + (size_t)l * HH * (3 * HH);
            const float2* whl = w_h + (size_t)l * HH * (3 * HH);
            const float2* bl  = b_rnn + (size_t)l * (3 * HH);
            float* hr = (l == 0 ? houtr0 : houtr1) + off;

            // Gc = Xc @ w_i + b   (N = 3H)
            cgemm_kernel<false, true><<<dim3(3 * HH / BN, chunk / BM), 256, 0, stream>>>(
                Xc, HH, wil, 3 * HH, bl, Gc, 3 * HH, HH);
            // Gc[:, :2H] += state @ w_h[:, :2H]
            cgemm_kernel<true, false><<<dim3(2 * HH / BN, chunk / BM), 256, 0, stream>>>(
                sl, HH, whl, 3 * HH, nullptr, Gc, 3 * HH, HH);
            // Gc[:, H:2H] = sigmoid(.) * state   (rs, in place)
            ew1_kernel<<<chunk * HH / 256, 256, 0, stream>>>(Gc, sl);
            // Gc[:, 2H:] += rs @ w_h[:, 2H:]
            cgemm_kernel<true, false><<<dim3(HH / BN, chunk / BM), 256, 0, stream>>>(
                Gc + HH, 3 * HH, whl + 2 * HH, 3 * HH, nullptr, Gc + 2 * HH, 3 * HH, HH);
            // hnew -> Xc (complex) and real part -> d_out
            ew2_kernel<<<chunk * HH / 256, 256, 0, stream>>>(Gc, sl, Xc, hr);
        }

        // out[p] = -LAM * Re(Xc @ w_out + b_out)
        outmm_kernel<<<(chunk * GG * 64 + 255) / 256, 256, 0, stream>>>(
            Xc, w_out, b_out, outf, r0, chunk);
    }
}

// Round 6
// 1864.371 us; speedup vs baseline: 4.1377x; 4.1377x over previous
//
#include <hip/hip_runtime.h>
#include <math.h>

// Problem constants
#define FF   81919
#define CC   16384
#define HH   512
#define NLL  2
#define GG   5
#define LAMF 0.01f

#define CH   (CC * HH)   // complex elements per state matrix

typedef short     short8 __attribute__((ext_vector_type(8)));
typedef float     f32x4  __attribute__((ext_vector_type(4)));

// d_out layout (float32 real parts): out[FF] | h0[CH] | h1[CH]
//
// d_ws layout:
//   bf16 expanded weights (ushort):
//     w_in_e [1024][64]    (65536)
//     w_i_e0 [3072][1024]  (3145728)   w_h_e0 [3072][1024]
//     w_i_e1 [3072][1024]              w_h_e1 [3072][1024]
//   float scratch per chunk: stk[chunk][64] | Xc[chunk][1024] | Gc[chunk][3072]
#define W_IN_E_SZ  (1024 * 64)
#define W_BIG_SZ   (3072 * 1024)
#define W_TOTAL_SH (W_IN_E_SZ + 4 * W_BIG_SZ)   // ushort count = 12648448

// ---------------------------------------------------------------------------
__device__ __forceinline__ float2 cmulf2(float2 a, float2 b) {
    return make_float2(a.x * b.x - a.y * b.y, a.x * b.y + a.y * b.x);
}
__device__ __forceinline__ float2 caddf2(float2 a, float2 b) {
    return make_float2(a.x + b.x, a.y + b.y);
}
__device__ __forceinline__ float sigmoidf_(float x) {
    return 1.0f / (1.0f + expf(-x));
}
__device__ __forceinline__ unsigned short f2bf(float f) {   // RNE fp32->bf16
    unsigned u = __float_as_uint(f);
    u = (u + 0x7FFF + ((u >> 16) & 1)) >> 16;
    return (unsigned short)u;
}

// ---------------------------------------------------------------------------
// 0) weight expansion: complex w[Kc][Nc] (row-major float2) ->
//    Bt[2Nc][ldb] bf16, k-contiguous per output column:
//      Bt[2n][2k]=re  Bt[2n][2k+1]=-im
//      Bt[2n+1][2k]=im  Bt[2n+1][2k+1]=re
//    zero-padded for 2k >= 2*Kc (ldb >= 2*Kc). One thread per (n, 8-kc group).
// ---------------------------------------------------------------------------
__global__ __launch_bounds__(256) void expand_kernel(const float2* __restrict__ w,
                                                     int Kc, int Nc, int ldb,
                                                     unsigned short* __restrict__ Bt) {
    int kg8 = ldb / 16;                      // 8-complex-k groups per column
    int i = blockIdx.x * 256 + threadIdx.x;  // [0, Nc*kg8)
    if (i >= Nc * kg8) return;
    int n = i % Nc, kg = i / Nc;
    unsigned short r0[16], r1[16];
#pragma unroll
    for (int j = 0; j < 8; j++) {
        int kc = kg * 8 + j;
        float re = 0.f, im = 0.f;
        if (kc < Kc) {
            float2 v = w[(size_t)kc * Nc + n];
            re = v.x; im = v.y;
        }
        unsigned short bre = f2bf(re), bim = f2bf(im), bnim = f2bf(-im);
        r0[2 * j] = bre;  r0[2 * j + 1] = bnim;
        r1[2 * j] = bim;  r1[2 * j + 1] = bre;
    }
    unsigned short* p0 = Bt + (size_t)(2 * n) * ldb + kg * 16;
    unsigned short* p1 = Bt + (size_t)(2 * n + 1) * ldb + kg * 16;
#pragma unroll
    for (int q = 0; q < 2; q++) {
        ((uint4*)p0)[q] = ((uint4*)r0)[q];
        ((uint4*)p1)[q] = ((uint4*)r1)[q];
    }
}

// ---------------------------------------------------------------------------
// 1) prep (per chunk): stk[c][64] fp32, cols 0..49 = interleaved log-compressed
//    stack (j = g*5+n complex slot), cols 50..63 zero. pos==FF pad -> 0.
// ---------------------------------------------------------------------------
__global__ __launch_bounds__(256) void prep_kernel(const float2* __restrict__ x,
                                                   const float2* __restrict__ extras,
                                                   float* __restrict__ stk,
                                                   int r0, int m) {
    int i = blockIdx.x * 256 + threadIdx.x;           // [0, m*32)
    if (i >= m * 32) return;
    int c = i >> 5, j = i & 31;
    float2 o = make_float2(0.f, 0.f);
    if (j < 25) {
        int g = j / 5, n = j - g * 5;
        int pos = (r0 + c) * 5 + g;
        float2 v = make_float2(0.f, 0.f);
        if (pos < FF) {
            v = (n == 0) ? x[pos] : extras[(size_t)(n - 1) * FF + pos];
        }
        float r = sqrtf(v.x * v.x + v.y * v.y);
        float sc = (r > 0.f) ? (log1pf(r) / r) : 0.f;
        o = make_float2(v.x * sc, v.y * sc);
    }
    stk[(size_t)c * 64 + 2 * j]     = o.x;
    stk[(size_t)c * 64 + 2 * j + 1] = o.y;
}

// ---------------------------------------------------------------------------
// 2) bf16 MFMA real GEMM: C[M][N] fp32 = (ACC?C:0) + A[M][K]fp32->bf16 @ Bt
//    Bt is [N][ldb] bf16 k-contiguous (pre-expanded). Tile 128x128, BK=32,
//    4 waves 2x2, 64x64 per wave via 4x4 16x16x32 fragments. nk = K/32.
// ---------------------------------------------------------------------------
#define LDP 40   // padded LDS row (shorts) per 32-k tile row

template <bool ACC, bool BIAS>
__global__ __launch_bounds__(256) void gemm_bf16(const float* __restrict__ A, int lda,
                                                 const unsigned short* __restrict__ Bt, int ldb,
                                                 const float* __restrict__ bias,
                                                 float* __restrict__ C, int ldc,
                                                 int nk) {
    __shared__ __align__(16) short As[128 * LDP];
    __shared__ __align__(16) short Bs[128 * LDP];

    int t = threadIdx.x;
    int m0 = blockIdx.y * 128, n0 = blockIdx.x * 128;
    int w = t >> 6, lane = t & 63;
    int wr = w >> 1, wc = w & 1;                    // wave 64x64 sub-tile
    int cl = lane & 15, rg = lane >> 4;             // frag col / row-group

    // staging assignments
    int srow = t >> 1, sh = t & 1;                  // A: row, 16-float half
    const float*          Ap = A + (size_t)(m0 + srow) * lda + sh * 16;
    const unsigned short* Bp = Bt + (size_t)(n0 + srow) * ldb + sh * 16;

    f32x4 acc[4][4] = {};

    for (int kt = 0; kt < nk; kt++) {
        // ---- stage A (fp32 -> bf16) ----
        const float4* ap = (const float4*)(Ap + kt * 32);
        float4 v0 = ap[0], v1 = ap[1], v2 = ap[2], v3 = ap[3];
        short8 pa0, pa1;
        pa0[0] = f2bf(v0.x); pa0[1] = f2bf(v0.y); pa0[2] = f2bf(v0.z); pa0[3] = f2bf(v0.w);
        pa0[4] = f2bf(v1.x); pa0[5] = f2bf(v1.y); pa0[6] = f2bf(v1.z); pa0[7] = f2bf(v1.w);
        pa1[0] = f2bf(v2.x); pa1[1] = f2bf(v2.y); pa1[2] = f2bf(v2.z); pa1[3] = f2bf(v2.w);
        pa1[4] = f2bf(v3.x); pa1[5] = f2bf(v3.y); pa1[6] = f2bf(v3.z); pa1[7] = f2bf(v3.w);
        // ---- stage B (bf16 copy) ----
        const uint4* bp = (const uint4*)(Bp + kt * 32);
        uint4 bv0 = bp[0], bv1 = bp[1];

        __syncthreads();   // previous compute done before overwriting LDS
        *(short8*)&As[srow * LDP + sh * 16]     = pa0;
        *(short8*)&As[srow * LDP + sh * 16 + 8] = pa1;
        *(uint4*)&Bs[srow * LDP + sh * 16]      = bv0;
        *(uint4*)&Bs[srow * LDP + sh * 16 + 8]  = bv1;
        __syncthreads();

        short8 af[4], bf[4];
#pragma unroll
        for (int mi = 0; mi < 4; mi++)
            af[mi] = *(const short8*)&As[(wr * 64 + mi * 16 + cl) * LDP + 8 * rg];
#pragma unroll
        for (int ni = 0; ni < 4; ni++)
            bf[ni] = *(const short8*)&Bs[(wc * 64 + ni * 16 + cl) * LDP + 8 * rg];
#pragma unroll
        for (int mi = 0; mi < 4; mi++)
#pragma unroll
            for (int ni = 0; ni < 4; ni++)
                acc[mi][ni] = __builtin_amdgcn_mfma_f32_16x16x32_bf16(
                    af[mi], bf[ni], acc[mi][ni], 0, 0, 0);
    }

    // ---- epilogue ----
#pragma unroll
    for (int ni = 0; ni < 4; ni++) {
        int col = n0 + wc * 64 + ni * 16 + cl;
        float bv = BIAS ? bias[col] : 0.f;
#pragma unroll
        for (int mi = 0; mi < 4; mi++) {
#pragma unroll
            for (int r = 0; r < 4; r++) {
                int row = m0 + wr * 64 + mi * 16 + rg * 4 + r;
                float v = acc[mi][ni][r] + bv;
                size_t idx = (size_t)row * ldc + col;
                if (ACC) v += C[idx];
                C[idx] = v;
            }
        }
    }
}

// ---------------------------------------------------------------------------
// 3) ew1 (per chunk): Gc[c][H+k] <- sigmoid(Gc[c][H+k]) * state[c][k]
//    Gc complex view: [m][1536]
// ---------------------------------------------------------------------------
__global__ __launch_bounds__(256) void ew1_kernel(float2* __restrict__ Gc,
                                                  const float2* __restrict__ state) {
    int i = blockIdx.x * 256 + threadIdx.x;  // [0, m*HH)
    int c = i >> 9, k = i & (HH - 1);
    size_t gi = (size_t)c * (3 * HH) + HH + k;
    float2 raw = Gc[gi];
    float2 r = make_float2(sigmoidf_(raw.x), sigmoidf_(raw.y));
    float2 s = state[i];
    Gc[gi] = cmulf2(r, s);
}

// ---------------------------------------------------------------------------
// 4) ew2 (per chunk): z=sig(Gc[:,:H]); a=tanh(Gc[:,2H:]);
//    hn=(1-z)*state+z*a ; Xc<-hn ; outr<-hn.re
// ---------------------------------------------------------------------------
__global__ __launch_bounds__(256) void ew2_kernel(const float2* __restrict__ Gc,
                                                  const float2* __restrict__ state,
                                                  float2* __restrict__ Xc,
                                                  float* __restrict__ outr) {
    int i = blockIdx.x * 256 + threadIdx.x;  // [0, m*HH)
    int c = i >> 9, k = i & (HH - 1);
    float2 zraw = Gc[(size_t)c * (3 * HH) + k];
    float2 araw = Gc[(size_t)c * (3 * HH) + 2 * HH + k];
    float2 z = make_float2(sigmoidf_(zraw.x), sigmoidf_(zraw.y));
    float2 a = make_float2(tanhf(araw.x), tanhf(araw.y));
    float2 s = state[i];
    float2 omz = make_float2(1.f - z.x, -z.y);
    float2 hn = caddf2(cmulf2(omz, s), cmulf2(z, a));
    Xc[i]   = hn;
    outr[i] = hn.x;
}

// ---------------------------------------------------------------------------
// 5) output matmul (per chunk): out[p] = -LAM*Re(Xc[c,:] . w_out[:,g] + b_out[g])
// ---------------------------------------------------------------------------
__global__ __launch_bounds__(256) void outmm_kernel(const float2* __restrict__ Xc,
                                                    const float2* __restrict__ w_out,
                                                    const float2* __restrict__ b_out,
                                                    float* __restrict__ out,
                                                    int r0, int m) {
    int wid = (blockIdx.x * 256 + threadIdx.x) >> 6;
    int lane = threadIdx.x & 63;
    if (wid >= m * GG) return;
    int c = wid / GG, g = wid - c * GG;
    const float2* arow = Xc + (size_t)c * HH;
    float2 acc = make_float2(0.f, 0.f);
    for (int k = lane; k < HH; k += 64) {
        acc = caddf2(acc, cmulf2(arow[k], w_out[k * GG + g]));
    }
#pragma unroll
    for (int off = 32; off > 0; off >>= 1) {
        acc.x += __shfl_down(acc.x, off);
        acc.y += __shfl_down(acc.y, off);
    }
    if (lane == 0) {
        int p = (r0 + c) * GG + g;
        if (p < FF) out[p] = -LAMF * (acc.x + b_out[g].x);
    }
}

// ---------------------------------------------------------------------------
// launch
// ---------------------------------------------------------------------------
extern "C" void kernel_launch(void* const* d_in, const int* in_sizes, int n_in,
                              void* d_out, int out_size, void* d_ws, size_t ws_size,
                              hipStream_t stream) {
    const float2* x      = (const float2*)d_in[0];
    const float2* extras = (const float2*)d_in[1];
    const float2* h      = (const float2*)d_in[2];
    const float2* w_in   = (const float2*)d_in[3];
    const float2* b_in   = (const float2*)d_in[4];
    const float2* w_i    = (const float2*)d_in[5];
    const float2* w_h    = (const float2*)d_in[6];
    const float2* b_rnn  = (const float2*)d_in[7];
    const float2* w_out  = (const float2*)d_in[8];
    const float2* b_out  = (const float2*)d_in[9];

    float* outf   = (float*)d_out;        // [FF]
    float* houtr0 = outf + FF;            // [CH]
    float* houtr1 = houtr0 + (size_t)CH;  // [CH]

    // ws: expanded bf16 weights | per-chunk float scratch
    unsigned short* wsh    = (unsigned short*)d_ws;
    unsigned short* w_in_e = wsh;
    unsigned short* w_i_e0 = w_in_e + W_IN_E_SZ;
    unsigned short* w_h_e0 = w_i_e0 + W_BIG_SZ;
    unsigned short* w_i_e1 = w_h_e0 + W_BIG_SZ;
    unsigned short* w_h_e1 = w_i_e1 + W_BIG_SZ;
    float* fbase = (float*)(wsh + W_TOTAL_SH);

    // chunk: weights (25.3MB) + chunk*16640 B <= ws_size   (round-4 proved >=34MB)
    size_t wbytes = (size_t)W_TOTAL_SH * 2;
    int chunk = 4096;
    while (chunk > 128 && wbytes + (size_t)chunk * 16640 > ws_size) chunk >>= 1;
    int nch = CC / chunk;

    float* stk = fbase;                        // [chunk*64]
    float* Xcf = stk + (size_t)chunk * 64;     // [chunk*1024]
    float* Gcf = Xcf + (size_t)chunk * 1024;   // [chunk*3072]
    float2* Xc = (float2*)Xcf;
    float2* Gc = (float2*)Gcf;

    // ---- expand weights (once per call) ----
    {
        int n1 = 512 * 4;        // w_in: Nc=512, kg8 = 64/16 = 4
        expand_kernel<<<(n1 + 255) / 256, 256, 0, stream>>>(w_in, 25, 512, 64, w_in_e);
        int n2 = 1536 * 64;      // w_i/w_h: Nc=1536, kg8 = 1024/16 = 64
        expand_kernel<<<(n2 + 255) / 256, 256, 0, stream>>>(w_i, 512, 1536, 1024, w_i_e0);
        expand_kernel<<<(n2 + 255) / 256, 256, 0, stream>>>(w_h, 512, 1536, 1024, w_h_e0);
        expand_kernel<<<(n2 + 255) / 256, 256, 0, stream>>>(w_i + (size_t)HH * 3 * HH, 512, 1536, 1024, w_i_e1);
        expand_kernel<<<(n2 + 255) / 256, 256, 0, stream>>>(w_h + (size_t)HH * 3 * HH, 512, 1536, 1024, w_h_e1);
    }

    for (int cb = 0; cb < nch; cb++) {
        int r0 = cb * chunk;
        size_t off = (size_t)r0 * HH;

        prep_kernel<<<(chunk * 32 + 255) / 256, 256, 0, stream>>>(x, extras, stk, r0, chunk);
        // Xc = stk @ w_in + b_in   (real: M x 64 x 1024)
        gemm_bf16<false, true><<<dim3(1024 / 128, chunk / 128), 256, 0, stream>>>(
            stk, 64, w_in_e, 64, (const float*)b_in, Xcf, 1024, 2);

        for (int l = 0; l < NLL; l++) {
            const float2* sl = h + (size_t)l * CH + off;
            const unsigned short* wie = (l == 0) ? w_i_e0 : w_i_e1;
            const unsigned short* whe = (l == 0) ? w_h_e0 : w_h_e1;
            const float* bl = (const float*)(b_rnn + (size_t)l * (3 * HH));
            float* hr = (l == 0 ? houtr0 : houtr1) + off;

            // Gc = Xc @ w_i + b      (M x 1024 x 3072)
            gemm_bf16<false, true><<<dim3(3072 / 128, chunk / 128), 256, 0, stream>>>(
                Xcf, 1024, wie, 1024, bl, Gcf, 3072, 32);
            // Gc[:, :2H] += state @ w_h[:, :2H]   (M x 1024 x 2048)
            gemm_bf16<true, false><<<dim3(2048 / 128, chunk / 128), 256, 0, stream>>>(
                (const float*)sl, 1024, whe, 1024, nullptr, Gcf, 3072, 32);
            // rs (in place in Gc r-slot)
            ew1_kernel<<<chunk * HH / 256, 256, 0, stream>>>(Gc, sl);
            // Gc[:, 2H:] += rs @ w_h[:, 2H:]      (M x 1024 x 1024)
            gemm_bf16<true, false><<<dim3(1024 / 128, chunk / 128), 256, 0, stream>>>(
                Gcf + 1024, 3072, whe + (size_t)2048 * 1024, 1024, nullptr, Gcf + 2048, 3072, 32);
            // hn -> Xc, hn.re -> d_out
            ew2_kernel<<<chunk * HH / 256, 256, 0, stream>>>(Gc, sl, Xc, hr);
        }

        outmm_kernel<<<(chunk * GG * 64 + 255) / 256, 256, 0, stream>>>(
            Xc, w_out, b_out, outf, r0, chunk);
    }
}

// Round 7
// 1096.578 us; speedup vs baseline: 7.0348x; 1.7002x over previous
//
#include <hip/hip_runtime.h>
#include <math.h>

// Problem constants
#define FF   81919
#define CC   16384
#define HH   512
#define NLL  2
#define GG   5
#define LAMF 0.01f

#define CH   (CC * HH)   // complex elements per state matrix

typedef short short8 __attribute__((ext_vector_type(8)));
typedef float f32x4  __attribute__((ext_vector_type(4)));

// d_out layout (float32 real parts): out[FF] | h0[CH] | h1[CH]
//
// d_ws layout (ushort units unless noted):
//   w_in_e [1024][64]                          65536
//   bzr0/bzr1 [2048][2048] (K = [w_h | w_i])   4194304 each
//   ba0/ba1   [1024][2048] (K = [w_i_a | w_h_a]) 2097152 each
//   XS  [chunk][3072] bf16  cols: 0:1024 s | 1024:2048 x | 2048:3072 rs
//   stk [chunk][64] bf16
//   ZR  [chunk][2048] fp32
//   Afp [chunk][1024] fp32
#define W_IN_E_SZ  (1024 * 64)
#define W_ZR_SZ    (2048 * 2048)
#define W_A_SZ     (1024 * 2048)
#define W_TOTAL_SH (W_IN_E_SZ + 2 * W_ZR_SZ + 2 * W_A_SZ)   // 12648448

// ---------------------------------------------------------------------------
__device__ __forceinline__ float sigmoidf_(float x) { return 1.0f / (1.0f + expf(-x)); }
__device__ __forceinline__ unsigned short f2bf(float f) {   // RNE fp32->bf16
    unsigned u = __float_as_uint(f);
    u = (u + 0x7FFF + ((u >> 16) & 1)) >> 16;
    return (unsigned short)u;
}
__device__ __forceinline__ float bf2f(unsigned short u) {
    return __uint_as_float(((unsigned)u) << 16);
}
__device__ __forceinline__ void gld_lds16(const unsigned short* g, unsigned short* l) {
    __builtin_amdgcn_global_load_lds(
        (const __attribute__((address_space(1))) void*)g,
        (__attribute__((address_space(3))) void*)l, 16, 0, 0);
}

// ---------------------------------------------------------------------------
// 0a) w_in expansion (K padded 25->32 complex, ldb=64 real)
//   Bt[2n][2k]=re Bt[2n][2k+1]=-im ; Bt[2n+1][2k]=im Bt[2n+1][2k+1]=re
// ---------------------------------------------------------------------------
__global__ __launch_bounds__(256) void expand_in(const float2* __restrict__ w,
                                                 unsigned short* __restrict__ Bt) {
    int i = blockIdx.x * 256 + threadIdx.x;  // [0, 512*4)
    if (i >= 512 * 4) return;
    int n = i & 511, kg = i >> 9;            // kg: 8-complex-k group (4 groups)
    unsigned short r0[16], r1[16];
#pragma unroll
    for (int j = 0; j < 8; j++) {
        int kc = kg * 8 + j;
        float re = 0.f, im = 0.f;
        if (kc < 25) { float2 v = w[(size_t)kc * 512 + n]; re = v.x; im = v.y; }
        r0[2 * j] = f2bf(re);  r0[2 * j + 1] = f2bf(-im);
        r1[2 * j] = f2bf(im);  r1[2 * j + 1] = f2bf(re);
    }
    unsigned short* p0 = Bt + (size_t)(2 * n) * 64 + kg * 16;
    unsigned short* p1 = Bt + (size_t)(2 * n + 1) * 64 + kg * 16;
#pragma unroll
    for (int q = 0; q < 2; q++) {
        ((uint4*)p0)[q] = ((uint4*)r0)[q];
        ((uint4*)p1)[q] = ((uint4*)r1)[q];
    }
}

// ---------------------------------------------------------------------------
// 0b) paired expansion: Bt[2Nc][ldb=2048], K = [part0: src0 | part1: src1],
//     each part Kc=512 complex. src pre-offset to its column block, ld = 1536.
// ---------------------------------------------------------------------------
__global__ __launch_bounds__(256) void expand2(const float2* __restrict__ src0,
                                               const float2* __restrict__ src1,
                                               int Nc,
                                               unsigned short* __restrict__ Bt) {
    int total = Nc * 2 * 64;                 // 64 = 512/8 kc-groups per part
    int i = blockIdx.x * 256 + threadIdx.x;
    if (i >= total) return;
    int kg = i / (2 * Nc);
    int rem = i - kg * 2 * Nc;
    int part = rem / Nc, n = rem - part * Nc;
    const float2* src = part ? src1 : src0;
    unsigned short r0[16], r1[16];
#pragma unroll
    for (int j = 0; j < 8; j++) {
        int kc = kg * 8 + j;
        float2 v = src[(size_t)kc * 1536 + n];
        r0[2 * j] = f2bf(v.x);  r0[2 * j + 1] = f2bf(-v.y);
        r1[2 * j] = f2bf(v.y);  r1[2 * j + 1] = f2bf(v.x);
    }
    size_t ko = (size_t)part * 1024 + kg * 16;
    unsigned short* p0 = Bt + (size_t)(2 * n) * 2048 + ko;
    unsigned short* p1 = Bt + (size_t)(2 * n + 1) * 2048 + ko;
#pragma unroll
    for (int q = 0; q < 2; q++) {
        ((uint4*)p0)[q] = ((uint4*)r0)[q];
        ((uint4*)p1)[q] = ((uint4*)r1)[q];
    }
}

// ---------------------------------------------------------------------------
// 1) prep: stk[c][64] bf16, cols 0..49 interleaved log-compressed, rest 0
// ---------------------------------------------------------------------------
__global__ __launch_bounds__(256) void prep_kernel(const float2* __restrict__ x,
                                                   const float2* __restrict__ extras,
                                                   unsigned short* __restrict__ stk,
                                                   int r0, int m) {
    int i = blockIdx.x * 256 + threadIdx.x;           // [0, m*32)
    if (i >= m * 32) return;
    int c = i >> 5, j = i & 31;
    float2 o = make_float2(0.f, 0.f);
    if (j < 25) {
        int g = j / 5, n = j - g * 5;
        int pos = (r0 + c) * 5 + g;
        float2 v = make_float2(0.f, 0.f);
        if (pos < FF) v = (n == 0) ? x[pos] : extras[(size_t)(n - 1) * FF + pos];
        float r = sqrtf(v.x * v.x + v.y * v.y);
        float sc = (r > 0.f) ? (log1pf(r) / r) : 0.f;
        o = make_float2(v.x * sc, v.y * sc);
    }
    stk[(size_t)c * 64 + 2 * j]     = f2bf(o.x);
    stk[(size_t)c * 64 + 2 * j + 1] = f2bf(o.y);
}

// ---------------------------------------------------------------------------
// 2) m97-style bf16 GEMM: C[M][N] = A[M][K]bf16 @ Bt[N][K]bf16 (+bias)
//    128x128 tile, BK=32, 4 waves 2x2, global_load_lds(16B), linear LDS.
// ---------------------------------------------------------------------------
template <bool BIAS, bool OUTBF16>
__global__ __launch_bounds__(256) void gemm_lds(const unsigned short* __restrict__ A, int lda,
                                                const unsigned short* __restrict__ Bt, int ldb,
                                                const float* __restrict__ bias,
                                                void* __restrict__ Cv, int ldc, int nk) {
    __shared__ __align__(16) unsigned short As[128 * 32];
    __shared__ __align__(16) unsigned short Bs[128 * 32];

    int t = threadIdx.x, lane = t & 63, w = t >> 6;
    int m0 = blockIdx.y * 128, n0 = blockIdx.x * 128;
    int wr = w >> 1, wc = w & 1;
    int cl = lane & 15, rg = lane >> 4;

    // staging addresses: seg s = w*2+i covers rows s*16..s*16+15 of the tile;
    // lane l -> row +(l>>2), 8-elem col group (l&3)*8. LDS dest = base + lane*16B.
    int lrow = lane >> 2, lcol = (lane & 3) * 8;
    const unsigned short* Ag0 = A  + (size_t)(m0 + w * 32 + lrow) * lda + lcol;
    const unsigned short* Ag1 = A  + (size_t)(m0 + w * 32 + 16 + lrow) * lda + lcol;
    const unsigned short* Bg0 = Bt + (size_t)(n0 + w * 32 + lrow) * ldb + lcol;
    const unsigned short* Bg1 = Bt + (size_t)(n0 + w * 32 + 16 + lrow) * ldb + lcol;
    unsigned short* Al0 = &As[w * 1024];
    unsigned short* Al1 = &As[w * 1024 + 512];
    unsigned short* Bl0 = &Bs[w * 1024];
    unsigned short* Bl1 = &Bs[w * 1024 + 512];

    f32x4 acc[4][4] = {};

    for (int kt = 0; kt < nk; kt++) {
        if (kt) __syncthreads();           // prev ds_reads done before overwrite
        gld_lds16(Ag0 + kt * 32, Al0);
        gld_lds16(Ag1 + kt * 32, Al1);
        gld_lds16(Bg0 + kt * 32, Bl0);
        gld_lds16(Bg1 + kt * 32, Bl1);
        __syncthreads();                   // drains vmcnt before use

        short8 af[4], bf[4];
#pragma unroll
        for (int mi = 0; mi < 4; mi++)
            af[mi] = *(const short8*)&As[(wr * 64 + mi * 16 + cl) * 32 + rg * 8];
#pragma unroll
        for (int ni = 0; ni < 4; ni++)
            bf[ni] = *(const short8*)&Bs[(wc * 64 + ni * 16 + cl) * 32 + rg * 8];
#pragma unroll
        for (int mi = 0; mi < 4; mi++)
#pragma unroll
            for (int ni = 0; ni < 4; ni++)
                acc[mi][ni] = __builtin_amdgcn_mfma_f32_16x16x32_bf16(
                    af[mi], bf[ni], acc[mi][ni], 0, 0, 0);
    }

#pragma unroll
    for (int ni = 0; ni < 4; ni++) {
        int col = n0 + wc * 64 + ni * 16 + cl;
        float bv = BIAS ? bias[col] : 0.f;
#pragma unroll
        for (int mi = 0; mi < 4; mi++) {
#pragma unroll
            for (int r = 0; r < 4; r++) {
                int row = m0 + wr * 64 + mi * 16 + rg * 4 + r;
                float v = acc[mi][ni][r] + bv;
                size_t idx = (size_t)row * ldc + col;
                if (OUTBF16) ((unsigned short*)Cv)[idx] = f2bf(v);
                else         ((float*)Cv)[idx] = v;
            }
        }
    }
}

// ---------------------------------------------------------------------------
// 3) cvt_state: XS s-slot <- bf16(h rows)   (per chunk, per layer)
// ---------------------------------------------------------------------------
__global__ __launch_bounds__(256) void cvt_state(const float* __restrict__ hf,
                                                 unsigned short* __restrict__ XS,
                                                 int r0, int m) {
    int i = blockIdx.x * 256 + threadIdx.x;    // [0, m*128)
    if (i >= m * 128) return;
    int c = i >> 7, q = i & 127;
    const float4* s = (const float4*)(hf + (size_t)(r0 + c) * 1024 + q * 8);
    float4 a = s[0], b = s[1];
    short8 o;
    o[0] = f2bf(a.x); o[1] = f2bf(a.y); o[2] = f2bf(a.z); o[3] = f2bf(a.w);
    o[4] = f2bf(b.x); o[5] = f2bf(b.y); o[6] = f2bf(b.z); o[7] = f2bf(b.w);
    *(short8*)(XS + (size_t)c * 3072 + q * 8) = o;
}

// ---------------------------------------------------------------------------
// 4) ew1: rs = sigmoid(ZR r-part) * state -> XS rs-slot (bf16). 4 complex/thread.
// ---------------------------------------------------------------------------
__global__ __launch_bounds__(256) void ew1_kernel(const float* __restrict__ ZR,
                                                  const float* __restrict__ hf,
                                                  unsigned short* __restrict__ XS,
                                                  int r0, int m) {
    int i = blockIdx.x * 256 + threadIdx.x;    // [0, m*128)
    if (i >= m * 128) return;
    int c = i >> 7, q = i & 127;
    const float4* rp = (const float4*)(ZR + (size_t)c * 2048 + 1024 + q * 8);
    const float4* sp = (const float4*)(hf + (size_t)(r0 + c) * 1024 + q * 8);
    float4 ra = rp[0], rb = rp[1], sa = sp[0], sb = sp[1];
    float rr[8] = {ra.x, ra.y, ra.z, ra.w, rb.x, rb.y, rb.z, rb.w};
    float ss[8] = {sa.x, sa.y, sa.z, sa.w, sb.x, sb.y, sb.z, sb.w};
    short8 o;
#pragma unroll
    for (int j = 0; j < 4; j++) {
        float zr = sigmoidf_(rr[2 * j]), zi = sigmoidf_(rr[2 * j + 1]);
        float sx = ss[2 * j], sy = ss[2 * j + 1];
        o[2 * j]     = f2bf(zr * sx - zi * sy);
        o[2 * j + 1] = f2bf(zr * sy + zi * sx);
    }
    *(short8*)(XS + (size_t)c * 3072 + 2048 + q * 8) = o;
}

// ---------------------------------------------------------------------------
// 5) ew2: z = sig(ZR z-part); a = tanh(Afp); hn = (1-z)*s + z*a (complex);
//    XS x-slot <- bf16(hn); hr <- hn.re (fp32)
// ---------------------------------------------------------------------------
__global__ __launch_bounds__(256) void ew2_kernel(const float* __restrict__ ZR,
                                                  const float* __restrict__ Afp,
                                                  const float* __restrict__ hf,
                                                  unsigned short* __restrict__ XS,
                                                  float* __restrict__ hr,
                                                  int r0, int m) {
    int i = blockIdx.x * 256 + threadIdx.x;    // [0, m*128)
    if (i >= m * 128) return;
    int c = i >> 7, q = i & 127;
    const float4* zp = (const float4*)(ZR + (size_t)c * 2048 + q * 8);
    const float4* ap = (const float4*)(Afp + (size_t)c * 1024 + q * 8);
    const float4* sp = (const float4*)(hf + (size_t)(r0 + c) * 1024 + q * 8);
    float4 za = zp[0], zb = zp[1], aa = ap[0], ab = ap[1], sa = sp[0], sb = sp[1];
    float zz[8] = {za.x, za.y, za.z, za.w, zb.x, zb.y, zb.z, zb.w};
    float av[8] = {aa.x, aa.y, aa.z, aa.w, ab.x, ab.y, ab.z, ab.w};
    float ss[8] = {sa.x, sa.y, sa.z, sa.w, sb.x, sb.y, sb.z, sb.w};
    short8 o;
    float4 re;
#pragma unroll
    for (int j = 0; j < 4; j++) {
        float zx = sigmoidf_(zz[2 * j]), zy = sigmoidf_(zz[2 * j + 1]);
        float ax = tanhf(av[2 * j]),     ay = tanhf(av[2 * j + 1]);
        float sx = ss[2 * j], sy = ss[2 * j + 1];
        // (1-z)*s + z*a, complex
        float ox = 1.f - zx, oy = -zy;
        float hx = ox * sx - oy * sy + zx * ax - zy * ay;
        float hy = ox * sy + oy * sx + zx * ay + zy * ax;
        o[2 * j] = f2bf(hx); o[2 * j + 1] = f2bf(hy);
        ((float*)&re)[j] = hx;
    }
    *(short8*)(XS + (size_t)c * 3072 + 1024 + q * 8) = o;
    *(float4*)(hr + (size_t)c * 512 + q * 4) = re;
}

// ---------------------------------------------------------------------------
// 6) output matmul: out[p] = -LAM * Re(xs_row . w_out[:,g] + b_out[g]);
//    one wave per (c,g); A read bf16 from XS x-slot
// ---------------------------------------------------------------------------
__global__ __launch_bounds__(256) void outmm_kernel(const unsigned short* __restrict__ XS,
                                                    const float2* __restrict__ w_out,
                                                    const float2* __restrict__ b_out,
                                                    float* __restrict__ out,
                                                    int r0, int m) {
    int wid = (blockIdx.x * 256 + threadIdx.x) >> 6;
    int lane = threadIdx.x & 63;
    if (wid >= m * GG) return;
    int c = wid / GG, g = wid - c * GG;
    const unsigned short* arow = XS + (size_t)c * 3072 + 1024;
    float ax = 0.f, ay = 0.f;
    for (int k = lane; k < HH; k += 64) {
        unsigned u = *(const unsigned*)(arow + 2 * k);
        float vx = bf2f((unsigned short)(u & 0xffff));
        float vy = bf2f((unsigned short)(u >> 16));
        float2 wv = w_out[k * GG + g];
        ax += vx * wv.x - vy * wv.y;
        ay += vx * wv.y + vy * wv.x;
    }
#pragma unroll
    for (int off = 32; off > 0; off >>= 1) {
        ax += __shfl_down(ax, off);
        ay += __shfl_down(ay, off);
    }
    if (lane == 0) {
        int p = (r0 + c) * GG + g;
        if (p < FF) out[p] = -LAMF * (ax + b_out[g].x);
    }
}

// ---------------------------------------------------------------------------
// launch
// ---------------------------------------------------------------------------
extern "C" void kernel_launch(void* const* d_in, const int* in_sizes, int n_in,
                              void* d_out, int out_size, void* d_ws, size_t ws_size,
                              hipStream_t stream) {
    const float2* x      = (const float2*)d_in[0];
    const float2* extras = (const float2*)d_in[1];
    const float2* h      = (const float2*)d_in[2];
    const float2* w_in   = (const float2*)d_in[3];
    const float2* b_in   = (const float2*)d_in[4];
    const float2* w_i    = (const float2*)d_in[5];
    const float2* w_h    = (const float2*)d_in[6];
    const float2* b_rnn  = (const float2*)d_in[7];
    const float2* w_out  = (const float2*)d_in[8];
    const float2* b_out  = (const float2*)d_in[9];

    float* outf   = (float*)d_out;        // [FF]
    float* houtr0 = outf + FF;            // [CH]
    float* houtr1 = houtr0 + (size_t)CH;  // [CH]

    unsigned short* wsh    = (unsigned short*)d_ws;
    unsigned short* w_in_e = wsh;
    unsigned short* bzr0   = w_in_e + W_IN_E_SZ;
    unsigned short* bzr1   = bzr0 + W_ZR_SZ;
    unsigned short* ba0    = bzr1 + W_ZR_SZ;
    unsigned short* ba1    = ba0 + W_A_SZ;

    // chunk: weights 25.3MB + chunk*18560B <= ws_size (round-6 proved >=94MB)
    size_t wbytes = (size_t)W_TOTAL_SH * 2;
    int chunk = 4096;
    while (chunk > 128 && wbytes + (size_t)chunk * 18560 > ws_size) chunk >>= 1;
    int nch = CC / chunk;

    unsigned short* XS  = ba1 + W_A_SZ;                   // [chunk*3072]
    unsigned short* stk = XS + (size_t)chunk * 3072;      // [chunk*64]
    float*          ZR  = (float*)(stk + (size_t)chunk * 64);   // [chunk*2048]
    float*          Afp = ZR + (size_t)chunk * 2048;            // [chunk*1024]

    // ---- expand weights ----
    expand_in<<<(512 * 4 + 255) / 256, 256, 0, stream>>>(w_in, w_in_e);
    for (int l = 0; l < NLL; l++) {
        const float2* wil = w_i + (size_t)l * HH * 1536;
        const float2* whl = w_h + (size_t)l * HH * 1536;
        unsigned short* bzr = l ? bzr1 : bzr0;
        unsigned short* ba  = l ? ba1 : ba0;
        // ZR weights: K = [s-part: w_h[:, :2H] | x-part: w_i[:, :2H]], Nc=1024
        expand2<<<(1024 * 2 * 64 + 255) / 256, 256, 0, stream>>>(whl, wil, 1024, bzr);
        // A weights: K = [x-part: w_i[:, 2H:] | rs-part: w_h[:, 2H:]], Nc=512
        expand2<<<(512 * 2 * 64 + 255) / 256, 256, 0, stream>>>(wil + 1024, whl + 1024, 512, ba);
    }

    for (int cb = 0; cb < nch; cb++) {
        int r0 = cb * chunk;
        int ewb = chunk * 128 / 256;

        prep_kernel<<<(chunk * 32 + 255) / 256, 256, 0, stream>>>(x, extras, stk, r0, chunk);
        // x-slot = stk @ w_in + b_in  (M x 64 x 1024, bf16 out into XS+1024)
        gemm_lds<true, true><<<dim3(8, chunk / 128), 256, 0, stream>>>(
            stk, 64, w_in_e, 64, (const float*)b_in, XS + 1024, 3072, 2);

        for (int l = 0; l < NLL; l++) {
            const float* hf = (const float*)(h + (size_t)l * CH);
            const float* bl = (const float*)(b_rnn + (size_t)l * 1536);
            float* hr = (l == 0 ? houtr0 : houtr1) + (size_t)r0 * HH;
            const unsigned short* bzr = l ? bzr1 : bzr0;
            const unsigned short* ba  = l ? ba1 : ba0;

            // s-slot <- bf16(h)
            cvt_state<<<ewb, 256, 0, stream>>>(hf, XS, r0, chunk);
            // ZR = XS[:, s|x] @ bzr + b[:2H]   (M x 2048 x 2048)
            gemm_lds<true, false><<<dim3(16, chunk / 128), 256, 0, stream>>>(
                XS, 3072, bzr, 2048, bl, ZR, 2048, 64);
            // rs-slot <- sigmoid(r) * s
            ew1_kernel<<<ewb, 256, 0, stream>>>(ZR, hf, XS, r0, chunk);
            // Afp = XS[:, x|rs] @ ba + b[2H:]  (M x 1024 x 2048)
            gemm_lds<true, false><<<dim3(8, chunk / 128), 256, 0, stream>>>(
                XS + 1024, 3072, ba, 2048, bl + 2048, Afp, 1024, 64);
            // hn -> XS x-slot (bf16) + real part -> d_out
            ew2_kernel<<<ewb, 256, 0, stream>>>(ZR, Afp, hf, XS, hr, r0, chunk);
        }

        outmm_kernel<<<(chunk * GG * 64 + 255) / 256, 256, 0, stream>>>(
            XS, w_out, b_out, outf, r0, chunk);
    }
}